// Round 13
// baseline (65.508 us; speedup 1.0000x reference)
//
#include <hip/hip_runtime.h>
#include <hip/hip_bf16.h>

// StatDynamicConv2d: routing MLP -> expert-mixed 3x3 conv (per-sample weights)
// B=32, Cin=Cout=128, H=W=64, E=4, K=3, pad=1, stride=1.
//
// ws layout:
//   [512, 512+16384)       dynb[32][128] f32
//   [32768, +9437184)      dynw[32][4cic][9tap][8mi][64lane][8] bf16
//                          (MFMA A-fragment order)
// conv reads x (f32) directly; per-cic restage = two-pass LDS transpose
// done IN-PLACE in xs. Pass2 is CHUNKED (3 rows at a time, tv[3]) to keep
// arch-VGPR demand under the 128-reg unified-file budget (r12 spilled).

typedef short bf16x8 __attribute__((ext_vector_type(8)));
typedef float f32x4  __attribute__((ext_vector_type(4)));

#define VMWAIT(n) asm volatile("s_waitcnt vmcnt(" #n ")" ::: "memory")
#define LGKM0()   asm volatile("s_waitcnt lgkmcnt(0)" ::: "memory")

static __device__ __forceinline__ unsigned short f2bf(float f) {
    unsigned u = __float_as_uint(f);
    u = u + 0x7FFFu + ((u >> 16) & 1u);   // round-to-nearest-even
    return (unsigned short)(u >> 16);
}

static __device__ __forceinline__ void gl2lds16(const unsigned short* g, unsigned short* l) {
    __builtin_amdgcn_global_load_lds(
        (const __attribute__((address_space(1))) unsigned int*)g,
        (__attribute__((address_space(3))) unsigned int*)l,
        16, 0, 0);
}

// ---------------- kernel P: dynamic weights (router inlined) ----------------
// grid 512 (= 128 co x 4 bgroups), 256 threads
__global__ void prep_kernel(const float* __restrict__ stats, const float* __restrict__ W1,
                            const float* __restrict__ b1, const float* __restrict__ W2,
                            const float* __restrict__ b2, const float* __restrict__ wexp,
                            const float* __restrict__ bexp, unsigned short* __restrict__ dynw,
                            float* __restrict__ dynb)
{
    __shared__ float ls[4*1152];
    __shared__ float lr[32*4];
    const int tid = threadIdx.x;
    const int co  = blockIdx.x & 127;
    const int bg  = blockIdx.x >> 7;

    if (tid < 32) {                   // recompute tiny router MLP per block (cheap)
        float s[6];
#pragma unroll
        for (int i = 0; i < 6; ++i) s[i] = stats[tid*6 + i];
        float h[16];
#pragma unroll
        for (int j = 0; j < 16; ++j) {
            float a = b1[j];
#pragma unroll
            for (int i = 0; i < 6; ++i) a += W1[j*6+i]*s[i];
            h[j] = a > 0.f ? a : 0.f;
        }
        float lg[4];
#pragma unroll
        for (int e = 0; e < 4; ++e) {
            float a = b2[e];
#pragma unroll
            for (int j = 0; j < 16; ++j) a += W2[e*16+j]*h[j];
            lg[e] = a;
        }
        float m = fmaxf(fmaxf(lg[0],lg[1]), fmaxf(lg[2],lg[3]));
        float ex[4], sum = 0.f;
#pragma unroll
        for (int e = 0; e < 4; ++e) { ex[e] = expf(lg[e]-m); sum += ex[e]; }
        float inv = 1.f / sum;
#pragma unroll
        for (int e = 0; e < 4; ++e) lr[tid*4+e] = ex[e]*inv;
    }
    for (int i = tid; i < 4*1152; i += 256) {
        int e = i / 1152, j = i - e*1152;
        ls[i] = wexp[((unsigned long long)(e*128 + co))*1152 + j];
    }
    __syncthreads();

    if (bg == 0 && tid < 32) {
        float sb = 0.f;
#pragma unroll
        for (int e = 0; e < 4; ++e) sb += lr[tid*4+e] * bexp[e*128 + co];
        dynb[tid*128 + co] = sb;
    }

    const int ci  = tid & 127;
    const int tp0 = tid >> 7;
    const int cic = ci >> 5;
    const int g   = (ci >> 3) & 3;
    const int jj  = ci & 7;
    const int mi  = co >> 4;
    const int l15 = co & 15;
    for (int bb = bg*8; bb < bg*8 + 8; ++bb) {
        float r0 = lr[bb*4+0], r1 = lr[bb*4+1], r2 = lr[bb*4+2], r3 = lr[bb*4+3];
#pragma unroll
        for (int pp = 0; pp < 5; ++pp) {
            int tap = 2*pp + tp0;
            if (tap < 9) {
                int j = ci*9 + tap;
                float v = r0*ls[j] + r1*ls[1152+j] + r2*ls[2*1152+j] + r3*ls[3*1152+j];
                dynw[((((unsigned long long)(bb*4 + cic)*9 + tap)*8 + mi)*64 + g*16 + l15)*8 + jj] = f2bf(v);
            }
        }
    }
}

// ---------------- kernel D: implicit-GEMM conv, bf16 MFMA ----------------
// grid 512 (32 b x 16 4-row tiles), 256 threads (4 waves), wave = 1 output
// row x full 128 co (mi=8). Weights staged to LDS (6-deep rotation, one
// vmcnt(0)+s_barrier per 3-tap phase). Per-cic x restage: two-pass LDS
// transpose in-place in xs (coalesced loads, no shuffles, chunked pass2).
__global__ __launch_bounds__(256, 2) void conv_kernel(
    const float* __restrict__ x,
    const unsigned short* __restrict__ dynw,
    const float* __restrict__ dynb,
    float* __restrict__ out)
{
    __shared__ __align__(16) unsigned short xs[6*66*32];      // 25344 B (6 rows x 4224 B)
    __shared__ __align__(16) unsigned short wsm[6][4096];     // 49152 B

    const int tid  = threadIdx.x;
    const int wave = tid >> 6;       // output row within tile (0..3)
    const int lane = tid & 63;
    const int l15  = lane & 15;
    const int g    = lane >> 4;
    const int pr    = tid >> 4;      // pass1: ci-pair id (0..15)
    const int c4    = tid & 15;      // pass1: col quad (0..15)
    const int p2col = tid & 63;      // pass2: column (0..63)
    const int p2cg  = tid >> 6;      // pass2: 8-ci chunk (0..3)

    // bijective XCD swizzle (512 blocks, 8 XCDs -> 64 contiguous per XCD)
    int bidx = ((blockIdx.x & 7) << 6) | (blockIdx.x >> 3);
    const int b  = bidx >> 4;
    const int r0 = (bidx & 15) << 2;

    f32x4 acc[8][4];
#pragma unroll
    for (int mi = 0; mi < 8; ++mi)
#pragma unroll
        for (int ni = 0; ni < 4; ++ni) acc[mi][ni] = (f32x4){0.f,0.f,0.f,0.f};

    const float* xsrcb = x + (unsigned long long)b*(128ull*64*64);
    const unsigned short* wsrcb = dynw + (unsigned long long)b*(4ull*9*4096);

    // ---- pass1: thread (pr,c4) loads ci 2pr,2pr+1 x cols 4c4..4c4+3 of row kk,
    //      packs bf16 pairs, writes raw uint4 into xs[row][bytes 0..4096) ----
#define P1ISSUE(kk)                                                            \
    do {                                                                       \
        int grow_ = r0 + (kk) - 1;                                             \
        int growc_ = grow_ < 0 ? 0 : (grow_ > 63 ? 63 : grow_);                \
        const float* xp_ = xsrcb + (unsigned)((cic_*32 + 2*pr)*4096)           \
                         + growc_*64 + c4*4;                                   \
        xv[(kk)%3][0] = *(const float4*)xp_;                                   \
        xv[(kk)%3][1] = *(const float4*)(xp_ + 4096);                          \
    } while (0)

#define P1PROC(kk)                                                             \
    do {                                                                       \
        int grow_ = r0 + (kk) - 1;                                             \
        bool oob_ = (grow_ < 0) || (grow_ > 63);                               \
        float4 va_ = xv[(kk)%3][0], vb_ = xv[(kk)%3][1];                       \
        unsigned w0_ = oob_ ? 0u : (f2bf(va_.x) | ((unsigned)f2bf(vb_.x) << 16)); \
        unsigned w1_ = oob_ ? 0u : (f2bf(va_.y) | ((unsigned)f2bf(vb_.y) << 16)); \
        unsigned w2_ = oob_ ? 0u : (f2bf(va_.z) | ((unsigned)f2bf(vb_.z) << 16)); \
        unsigned w3_ = oob_ ? 0u : (f2bf(va_.w) | ((unsigned)f2bf(vb_.w) << 16)); \
        *(uint4*)((char*)xs + (kk)*4224 + pr*256 + c4*16)                      \
            = make_uint4(w0_, w1_, w2_, w3_);                                  \
    } while (0)

    // ---- full restage: issue W(next phase) first, then rolling pass1 ladder,
    //      then in-place pass2 chunked 3-rows-at-a-time (tv[3] keeps register
    //      demand low; chunks are row-disjoint so inter-chunk race-free) ----
#define XSTAGE2(CIC_, WFIRST_)                                                 \
    do {                                                                       \
        const int cic_ = (CIC_);                                               \
        _Pragma("unroll")                                                      \
        for (int t = 0; t < 3; ++t) {                                          \
            const unsigned short* wsrc_ = wsrcb + (unsigned)(((WFIRST_) + t)*4096); \
            unsigned short* wd_ = wsm[((WFIRST_) + t) % 6];                    \
            gl2lds16(wsrc_ + (unsigned)tid*8,       wd_ + (unsigned)tid*8);    \
            gl2lds16(wsrc_ + (unsigned)(tid+256)*8, wd_ + (unsigned)(tid+256)*8); \
        }                                                                      \
        {                                                                      \
            float4 xv[3][2];                                                   \
            P1ISSUE(0); P1ISSUE(1); P1ISSUE(2);                                \
            VMWAIT(4); P1PROC(0); P1ISSUE(3);                                  \
            VMWAIT(4); P1PROC(1); P1ISSUE(4);                                  \
            VMWAIT(4); P1PROC(2); P1ISSUE(5);                                  \
            VMWAIT(4); P1PROC(3);                                              \
            VMWAIT(2); P1PROC(4);                                              \
            VMWAIT(0); P1PROC(5);                                              \
        }                                                                      \
        LGKM0();                                                               \
        __builtin_amdgcn_s_barrier();                                          \
        __builtin_amdgcn_sched_barrier(0);                                     \
        _Pragma("unroll")                                                      \
        for (int h = 0; h < 2; ++h) {                                          \
            uint4 tv[3];                                                       \
            _Pragma("unroll")                                                  \
            for (int r = 0; r < 3; ++r) {                                      \
                const char* rb_ = (const char*)xs + (h*3 + r)*4224             \
                                + p2cg*1024 + p2col*4;                         \
                tv[r].x = *(const unsigned*)(rb_);                             \
                tv[r].y = *(const unsigned*)(rb_ + 256);                       \
                tv[r].z = *(const unsigned*)(rb_ + 512);                       \
                tv[r].w = *(const unsigned*)(rb_ + 768);                       \
            }                                                                  \
            LGKM0();                                                           \
            __builtin_amdgcn_s_barrier();                                      \
            __builtin_amdgcn_sched_barrier(0);                                 \
            int lcol_ = p2col + 1;                                             \
            int wb_   = ((p2cg + (lcol_ >> 1)) & 3) << 4;                      \
            _Pragma("unroll")                                                  \
            for (int r = 0; r < 3; ++r)                                        \
                *(uint4*)((char*)xs + (h*3 + r)*4224 + lcol_*64 + wb_) = tv[r];\
        }                                                                      \
        if (tid < 24)                                                          \
            *(uint4*)((char*)xs + (tid>>2)*4224 + (tid&3)*16)                  \
                = make_uint4(0,0,0,0);                                         \
        LGKM0();                                                               \
        __builtin_amdgcn_s_barrier();                                          \
        __builtin_amdgcn_sched_barrier(0);                                     \
    } while (0)

    // prologue: zero lcol65 (never touched by restage), stage cic0 + W(0..2)
    if (tid < 24)
        *(uint4*)((char*)xs + (tid>>2)*4224 + 65*64 + (tid&3)*16) = make_uint4(0,0,0,0);
    XSTAGE2(0, 0);

#pragma unroll
    for (int p = 0; p < 12; ++p) {
        const int cic = p / 3;
        if (p > 0) {
            // bar A: W(p) (issued a full phase ago) landed; cheap drain
            VMWAIT(0);
            __builtin_amdgcn_s_barrier();
            __builtin_amdgcn_sched_barrier(0);
        }
        if ((p % 3) == 0 && p > 0) {
            // cic boundary: restage xs in-place (coalesced 2-pass transpose);
            // issues W(3p+3..3p+5) inside; ends with barrier.
            XSTAGE2(cic, 3*p + 3);
        } else if (p < 11) {
            // steady: issue next phase's 3 weight tiles (reads {3p..3p+2}%6,
            // writes {3p+3..3p+5}%6 — disjoint)
#pragma unroll
            for (int t = 0; t < 3; ++t) {
                const int s = 3*p + 3 + t;
                const unsigned short* wsrc = wsrcb + (unsigned)(s*4096);
                unsigned short* wd = wsm[s % 6];
                gl2lds16(wsrc + (unsigned)tid*8,       wd + (unsigned)tid*8);
                gl2lds16(wsrc + (unsigned)(tid+256)*8, wd + (unsigned)(tid+256)*8);
            }
        }
        // compute 3 taps (ky = p%3, kx = 0..2), no intervening sync
        const int ky   = p % 3;
        const int lrow = wave + ky;
        __builtin_amdgcn_s_setprio(1);
#pragma unroll
        for (int kx = 0; kx < 3; ++kx) {
            const unsigned short* wb = wsm[(3*p + kx) % 6];
            bf16x8 afrag[8];
#pragma unroll
            for (int mi = 0; mi < 8; ++mi)
                afrag[mi] = *(const bf16x8*)(wb + (unsigned)((mi*64 + lane)*8));
#pragma unroll
            for (int ni = 0; ni < 4; ++ni) {
                int lcol = 16*ni + l15 + kx;
                int boff = (lrow*66 + lcol)*64 + (((g + (lcol >> 1)) & 3) << 4);
                bf16x8 bfrag = *(const bf16x8*)((const char*)xs + boff);
#pragma unroll
                for (int mi = 0; mi < 8; ++mi)
                    acc[mi][ni] = __builtin_amdgcn_mfma_f32_16x16x32_bf16(
                                      afrag[mi], bfrag, acc[mi][ni], 0, 0, 0);
            }
        }
        __builtin_amdgcn_s_setprio(0);
    }

    // epilogue: co = 16*mi + g*4 + r ; y = r0 + wave ; x = 16*ni + l15
    const int y = r0 + wave;
#pragma unroll
    for (int mi = 0; mi < 8; ++mi) {
#pragma unroll
        for (int r = 0; r < 4; ++r) {
            int co = 16*mi + g*4 + r;
            float bias = dynb[b*128 + co];
            float* op = out + (((unsigned long long)(b*128 + co))*64 + y)*64;
#pragma unroll
            for (int ni = 0; ni < 4; ++ni)
                op[16*ni + l15] = acc[mi][ni][r] + bias;
        }
    }
#undef XSTAGE2
#undef P1PROC
#undef P1ISSUE
}

extern "C" void kernel_launch(void* const* d_in, const int* in_sizes, int n_in,
                              void* d_out, int out_size, void* d_ws, size_t ws_size,
                              hipStream_t stream)
{
    const float* x     = (const float*)d_in[0];
    const float* stats = (const float*)d_in[1];
    const float* W1    = (const float*)d_in[2];
    const float* b1    = (const float*)d_in[3];
    const float* W2    = (const float*)d_in[4];
    const float* b2    = (const float*)d_in[5];
    const float* wexp  = (const float*)d_in[6];
    const float* bexp  = (const float*)d_in[7];
    float* out = (float*)d_out;

    char* ws = (char*)d_ws;
    float* dynb           = (float*)(ws + 512);                      // 16 KB
    unsigned short* dynw  = (unsigned short*)(ws + 32768);           // 9,437,184 B

    prep_kernel<<<512, 256, 0, stream>>>(stats, W1, b1, W2, b2, wexp, bexp, dynw, dynb);
    conv_kernel<<<512, 256, 0, stream>>>(x, dynw, dynb, out);
}

// Round 14
// 64.584 us; speedup vs baseline: 1.0143x; 1.0143x over previous
//
#include <hip/hip_runtime.h>
#include <hip/hip_bf16.h>

// StatDynamicConv2d: routing MLP -> expert-mixed 3x3 conv (per-sample weights)
// B=32, Cin=Cout=128, H=W=64, E=4, K=3, pad=1, stride=1.
//
// ws layout:
//   [512, 512+16384)       dynb[32][128] f32
//   [32768, +9437184)      dynw[32][4cic][9tap][8mi][64lane][8] bf16
//                          (MFMA A-fragment order)
// conv reads x (f32) directly; per-cic restage = two-pass LDS transpose
// in-place in xs. Register-pressure discipline (r13 spilled ~28MB):
//  - MFMA loop preloads bfrag[4] (16 regs) instead of afrag[8] (32)
//  - pass1 load window depth 2 (xv[2][2])
//  - phase loop #pragma unroll 2 (parity-static %6 indices, smaller body)

typedef short bf16x8 __attribute__((ext_vector_type(8)));
typedef float f32x4  __attribute__((ext_vector_type(4)));

#define VMWAIT(n) asm volatile("s_waitcnt vmcnt(" #n ")" ::: "memory")
#define LGKM0()   asm volatile("s_waitcnt lgkmcnt(0)" ::: "memory")

static __device__ __forceinline__ unsigned short f2bf(float f) {
    unsigned u = __float_as_uint(f);
    u = u + 0x7FFFu + ((u >> 16) & 1u);   // round-to-nearest-even
    return (unsigned short)(u >> 16);
}

static __device__ __forceinline__ void gl2lds16(const unsigned short* g, unsigned short* l) {
    __builtin_amdgcn_global_load_lds(
        (const __attribute__((address_space(1))) unsigned int*)g,
        (__attribute__((address_space(3))) unsigned int*)l,
        16, 0, 0);
}

// ---------------- kernel P: dynamic weights (router inlined) ----------------
// grid 512 (= 128 co x 4 bgroups), 256 threads
__global__ void prep_kernel(const float* __restrict__ stats, const float* __restrict__ W1,
                            const float* __restrict__ b1, const float* __restrict__ W2,
                            const float* __restrict__ b2, const float* __restrict__ wexp,
                            const float* __restrict__ bexp, unsigned short* __restrict__ dynw,
                            float* __restrict__ dynb)
{
    __shared__ float ls[4*1152];
    __shared__ float lr[32*4];
    const int tid = threadIdx.x;
    const int co  = blockIdx.x & 127;
    const int bg  = blockIdx.x >> 7;

    if (tid < 32) {                   // recompute tiny router MLP per block (cheap)
        float s[6];
#pragma unroll
        for (int i = 0; i < 6; ++i) s[i] = stats[tid*6 + i];
        float h[16];
#pragma unroll
        for (int j = 0; j < 16; ++j) {
            float a = b1[j];
#pragma unroll
            for (int i = 0; i < 6; ++i) a += W1[j*6+i]*s[i];
            h[j] = a > 0.f ? a : 0.f;
        }
        float lg[4];
#pragma unroll
        for (int e = 0; e < 4; ++e) {
            float a = b2[e];
#pragma unroll
            for (int j = 0; j < 16; ++j) a += W2[e*16+j]*h[j];
            lg[e] = a;
        }
        float m = fmaxf(fmaxf(lg[0],lg[1]), fmaxf(lg[2],lg[3]));
        float ex[4], sum = 0.f;
#pragma unroll
        for (int e = 0; e < 4; ++e) { ex[e] = expf(lg[e]-m); sum += ex[e]; }
        float inv = 1.f / sum;
#pragma unroll
        for (int e = 0; e < 4; ++e) lr[tid*4+e] = ex[e]*inv;
    }
    for (int i = tid; i < 4*1152; i += 256) {
        int e = i / 1152, j = i - e*1152;
        ls[i] = wexp[((unsigned long long)(e*128 + co))*1152 + j];
    }
    __syncthreads();

    if (bg == 0 && tid < 32) {
        float sb = 0.f;
#pragma unroll
        for (int e = 0; e < 4; ++e) sb += lr[tid*4+e] * bexp[e*128 + co];
        dynb[tid*128 + co] = sb;
    }

    const int ci  = tid & 127;
    const int tp0 = tid >> 7;
    const int cic = ci >> 5;
    const int g   = (ci >> 3) & 3;
    const int jj  = ci & 7;
    const int mi  = co >> 4;
    const int l15 = co & 15;
    for (int bb = bg*8; bb < bg*8 + 8; ++bb) {
        float r0 = lr[bb*4+0], r1 = lr[bb*4+1], r2 = lr[bb*4+2], r3 = lr[bb*4+3];
#pragma unroll
        for (int pp = 0; pp < 5; ++pp) {
            int tap = 2*pp + tp0;
            if (tap < 9) {
                int j = ci*9 + tap;
                float v = r0*ls[j] + r1*ls[1152+j] + r2*ls[2*1152+j] + r3*ls[3*1152+j];
                dynw[((((unsigned long long)(bb*4 + cic)*9 + tap)*8 + mi)*64 + g*16 + l15)*8 + jj] = f2bf(v);
            }
        }
    }
}

// ---------------- kernel D: implicit-GEMM conv, bf16 MFMA ----------------
// grid 512 (32 b x 16 4-row tiles), 256 threads (4 waves), wave = 1 output
// row x full 128 co (mi=8). Weights staged to LDS (6-deep rotation, one
// vmcnt(0)+s_barrier per 3-tap phase). Per-cic x restage: two-pass LDS
// transpose in-place in xs.
__global__ __launch_bounds__(256, 2) void conv_kernel(
    const float* __restrict__ x,
    const unsigned short* __restrict__ dynw,
    const float* __restrict__ dynb,
    float* __restrict__ out)
{
    __shared__ __align__(16) unsigned short xs[6*66*32];      // 25344 B (6 rows x 4224 B)
    __shared__ __align__(16) unsigned short wsm[6][4096];     // 49152 B

    const int tid  = threadIdx.x;
    const int wave = tid >> 6;       // output row within tile (0..3)
    const int lane = tid & 63;
    const int l15  = lane & 15;
    const int g    = lane >> 4;
    const int pr    = tid >> 4;      // pass1: ci-pair id (0..15)
    const int c4    = tid & 15;      // pass1: col quad (0..15)
    const int p2col = tid & 63;      // pass2: column (0..63)
    const int p2cg  = tid >> 6;      // pass2: 8-ci chunk (0..3)

    // bijective XCD swizzle (512 blocks, 8 XCDs -> 64 contiguous per XCD)
    int bidx = ((blockIdx.x & 7) << 6) | (blockIdx.x >> 3);
    const int b  = bidx >> 4;
    const int r0 = (bidx & 15) << 2;

    f32x4 acc[8][4];
#pragma unroll
    for (int mi = 0; mi < 8; ++mi)
#pragma unroll
        for (int ni = 0; ni < 4; ++ni) acc[mi][ni] = (f32x4){0.f,0.f,0.f,0.f};

    const float* xsrcb = x + (unsigned long long)b*(128ull*64*64);
    const unsigned short* wsrcb = dynw + (unsigned long long)b*(4ull*9*4096);

    // ---- pass1: thread (pr,c4) loads ci 2pr,2pr+1 x cols 4c4..4c4+3 of row kk,
    //      packs bf16 pairs, writes raw uint4 into xs[row][bytes 0..4096) ----
#define P1ISSUE(kk)                                                            \
    do {                                                                       \
        int grow_ = r0 + (kk) - 1;                                             \
        int growc_ = grow_ < 0 ? 0 : (grow_ > 63 ? 63 : grow_);                \
        const float* xp_ = xsrcb + (unsigned)((cic_*32 + 2*pr)*4096)           \
                         + growc_*64 + c4*4;                                   \
        xv[(kk)&1][0] = *(const float4*)xp_;                                   \
        xv[(kk)&1][1] = *(const float4*)(xp_ + 4096);                          \
    } while (0)

#define P1PROC(kk)                                                             \
    do {                                                                       \
        int grow_ = r0 + (kk) - 1;                                             \
        bool oob_ = (grow_ < 0) || (grow_ > 63);                               \
        float4 va_ = xv[(kk)&1][0], vb_ = xv[(kk)&1][1];                       \
        unsigned w0_ = oob_ ? 0u : (f2bf(va_.x) | ((unsigned)f2bf(vb_.x) << 16)); \
        unsigned w1_ = oob_ ? 0u : (f2bf(va_.y) | ((unsigned)f2bf(vb_.y) << 16)); \
        unsigned w2_ = oob_ ? 0u : (f2bf(va_.z) | ((unsigned)f2bf(vb_.z) << 16)); \
        unsigned w3_ = oob_ ? 0u : (f2bf(va_.w) | ((unsigned)f2bf(vb_.w) << 16)); \
        *(uint4*)((char*)xs + (kk)*4224 + pr*256 + c4*16)                      \
            = make_uint4(w0_, w1_, w2_, w3_);                                  \
    } while (0)

    // ---- full restage: issue W(next phase) first (drained early, L2-fast),
    //      rolling depth-2 pass1 ladder, then in-place chunked pass2 ----
#define XSTAGE2(CIC_, WFIRST_, WI0_)                                           \
    do {                                                                       \
        const int cic_ = (CIC_);                                               \
        _Pragma("unroll")                                                      \
        for (int t = 0; t < 3; ++t) {                                          \
            const unsigned short* wsrc_ = wsrcb + (unsigned)(((WFIRST_) + t)*4096); \
            unsigned short* wd_ = wsm[((WI0_) + t) % 6];                       \
            gl2lds16(wsrc_ + (unsigned)tid*8,       wd_ + (unsigned)tid*8);    \
            gl2lds16(wsrc_ + (unsigned)(tid+256)*8, wd_ + (unsigned)(tid+256)*8); \
        }                                                                      \
        {                                                                      \
            float4 xv[2][2];                                                   \
            P1ISSUE(0); P1ISSUE(1);                                            \
            VMWAIT(2); P1PROC(0); P1ISSUE(2);                                  \
            VMWAIT(2); P1PROC(1); P1ISSUE(3);                                  \
            VMWAIT(2); P1PROC(2); P1ISSUE(4);                                  \
            VMWAIT(2); P1PROC(3); P1ISSUE(5);                                  \
            VMWAIT(2); P1PROC(4);                                              \
            VMWAIT(0); P1PROC(5);                                              \
        }                                                                      \
        LGKM0();                                                               \
        __builtin_amdgcn_s_barrier();                                          \
        __builtin_amdgcn_sched_barrier(0);                                     \
        _Pragma("unroll")                                                      \
        for (int h = 0; h < 2; ++h) {                                          \
            uint4 tv[3];                                                       \
            _Pragma("unroll")                                                  \
            for (int r = 0; r < 3; ++r) {                                      \
                const char* rb_ = (const char*)xs + (h*3 + r)*4224             \
                                + p2cg*1024 + p2col*4;                         \
                tv[r].x = *(const unsigned*)(rb_);                             \
                tv[r].y = *(const unsigned*)(rb_ + 256);                       \
                tv[r].z = *(const unsigned*)(rb_ + 512);                       \
                tv[r].w = *(const unsigned*)(rb_ + 768);                       \
            }                                                                  \
            LGKM0();                                                           \
            __builtin_amdgcn_s_barrier();                                      \
            __builtin_amdgcn_sched_barrier(0);                                 \
            int lcol_ = p2col + 1;                                             \
            int wb_   = ((p2cg + (lcol_ >> 1)) & 3) << 4;                      \
            _Pragma("unroll")                                                  \
            for (int r = 0; r < 3; ++r)                                        \
                *(uint4*)((char*)xs + (h*3 + r)*4224 + lcol_*64 + wb_) = tv[r];\
        }                                                                      \
        if (tid < 24)                                                          \
            *(uint4*)((char*)xs + (tid>>2)*4224 + (tid&3)*16)                  \
                = make_uint4(0,0,0,0);                                         \
        LGKM0();                                                               \
        __builtin_amdgcn_s_barrier();                                          \
        __builtin_amdgcn_sched_barrier(0);                                     \
    } while (0)

    // prologue: zero lcol65 (never touched by restage), stage cic0 + W(0..2)
    if (tid < 24)
        *(uint4*)((char*)xs + (tid>>2)*4224 + 65*64 + (tid&3)*16) = make_uint4(0,0,0,0);
    XSTAGE2(0, 0, 0);

    // 12 phases = 4 cic x 3 ky-phases. unroll 2 over cic: parity makes all
    // wsm %6 indices compile-time (9cic ≡ 3(cic&1) mod 6).
#pragma unroll 2
    for (int cic = 0; cic < 4; ++cic) {
        const int par3 = 3*(cic & 1);   // static after unroll-2
#pragma unroll
        for (int q = 0; q < 3; ++q) {
            if (cic > 0 || q > 0) {
                // bar A: everything issued >= 1 phase ago landed; cheap drain
                VMWAIT(0);
                __builtin_amdgcn_s_barrier();
                __builtin_amdgcn_sched_barrier(0);
            }
            if (q == 0 && cic > 0) {
                // cic boundary: in-place restage + W(3p+3..) issue inside
                XSTAGE2(cic, 9*cic + 3, (par3 + 3) % 6);
            } else if (!(cic == 3 && q == 2)) {
                // steady: issue next phase's 3 W tiles
                // reads this phase: wsm[(par3+3q+kx)%6]; writes: +3 — disjoint
#pragma unroll
                for (int t = 0; t < 3; ++t) {
                    const unsigned short* wsrc = wsrcb
                        + (unsigned)((9*cic + 3*q + 3 + t)*4096);
                    unsigned short* wd = wsm[(par3 + 3*q + 3 + t) % 6];
                    gl2lds16(wsrc + (unsigned)tid*8,       wd + (unsigned)tid*8);
                    gl2lds16(wsrc + (unsigned)(tid+256)*8, wd + (unsigned)(tid+256)*8);
                }
            }
            // compute 3 taps (ky = q, kx = 0..2), no intervening sync
            const int lrow = wave + q;
            __builtin_amdgcn_s_setprio(1);
#pragma unroll
            for (int kx = 0; kx < 3; ++kx) {
                const unsigned short* wb = wsm[(par3 + 3*q + kx) % 6];
                bf16x8 bfrag[4];
#pragma unroll
                for (int ni = 0; ni < 4; ++ni) {
                    int lcol = 16*ni + l15 + kx;
                    int boff = (lrow*66 + lcol)*64 + (((g + (lcol >> 1)) & 3) << 4);
                    bfrag[ni] = *(const bf16x8*)((const char*)xs + boff);
                }
#pragma unroll
                for (int mi = 0; mi < 8; ++mi) {
                    bf16x8 afrag = *(const bf16x8*)(wb + (unsigned)((mi*64 + lane)*8));
#pragma unroll
                    for (int ni = 0; ni < 4; ++ni)
                        acc[mi][ni] = __builtin_amdgcn_mfma_f32_16x16x32_bf16(
                                          afrag, bfrag[ni], acc[mi][ni], 0, 0, 0);
                }
            }
            __builtin_amdgcn_s_setprio(0);
        }
    }

    // epilogue: co = 16*mi + g*4 + r ; y = r0 + wave ; x = 16*ni + l15
    const int y = r0 + wave;
#pragma unroll
    for (int mi = 0; mi < 8; ++mi) {
#pragma unroll
        for (int r = 0; r < 4; ++r) {
            int co = 16*mi + g*4 + r;
            float bias = dynb[b*128 + co];
            float* op = out + (((unsigned long long)(b*128 + co))*64 + y)*64;
#pragma unroll
            for (int ni = 0; ni < 4; ++ni)
                op[16*ni + l15] = acc[mi][ni][r] + bias;
        }
    }
#undef XSTAGE2
#undef P1PROC
#undef P1ISSUE
}

extern "C" void kernel_launch(void* const* d_in, const int* in_sizes, int n_in,
                              void* d_out, int out_size, void* d_ws, size_t ws_size,
                              hipStream_t stream)
{
    const float* x     = (const float*)d_in[0];
    const float* stats = (const float*)d_in[1];
    const float* W1    = (const float*)d_in[2];
    const float* b1    = (const float*)d_in[3];
    const float* W2    = (const float*)d_in[4];
    const float* b2    = (const float*)d_in[5];
    const float* wexp  = (const float*)d_in[6];
    const float* bexp  = (const float*)d_in[7];
    float* out = (float*)d_out;

    char* ws = (char*)d_ws;
    float* dynb           = (float*)(ws + 512);                      // 16 KB
    unsigned short* dynw  = (unsigned short*)(ws + 32768);           // 9,437,184 B

    prep_kernel<<<512, 256, 0, stream>>>(stats, W1, b1, W2, b2, wexp, bexp, dynw, dynb);
    conv_kernel<<<512, 256, 0, stream>>>(x, dynw, dynb, out);
}

// Round 15
// 60.255 us; speedup vs baseline: 1.0872x; 1.0718x over previous
//
#include <hip/hip_runtime.h>
#include <hip/hip_bf16.h>

// StatDynamicConv2d: routing MLP -> expert-mixed 3x3 conv (per-sample weights)
// B=32, Cin=Cout=128, H=W=64, E=4, K=3, pad=1, stride=1.
//
// ws layout:
//   [512, 512+16384)       dynb[32][128] f32
//   [32768, +9437184)      dynw[32][4cic][9tap][8mi][64lane][8] bf16
//                          (MFMA A-fragment order)
// conv reads x (f32) directly. xs keeps the RAW staged layout
// [6 rows][16 ci-pair][68 words] (u32 = 2 bf16 ci for one col; words 0..63 =
// cols, word 64/65 = zero halo). B-frags are read as 4x ds_read_b32 at
// pr-stride 272B -- no LDS transpose pass, no swizzle, no shuffles.

typedef short bf16x8 __attribute__((ext_vector_type(8)));
typedef float f32x4  __attribute__((ext_vector_type(4)));
typedef unsigned u32x4 __attribute__((ext_vector_type(4)));

#define VMWAIT(n) asm volatile("s_waitcnt vmcnt(" #n ")" ::: "memory")
#define LGKM0()   asm volatile("s_waitcnt lgkmcnt(0)" ::: "memory")

static __device__ __forceinline__ unsigned short f2bf(float f) {
    unsigned u = __float_as_uint(f);
    u = u + 0x7FFFu + ((u >> 16) & 1u);   // round-to-nearest-even
    return (unsigned short)(u >> 16);
}

static __device__ __forceinline__ void gl2lds16(const unsigned short* g, unsigned short* l) {
    __builtin_amdgcn_global_load_lds(
        (const __attribute__((address_space(1))) unsigned int*)g,
        (__attribute__((address_space(3))) unsigned int*)l,
        16, 0, 0);
}

// ---------------- kernel P: dynamic weights (router inlined) ----------------
// grid 512 (= 128 co x 4 bgroups), 256 threads
__global__ void prep_kernel(const float* __restrict__ stats, const float* __restrict__ W1,
                            const float* __restrict__ b1, const float* __restrict__ W2,
                            const float* __restrict__ b2, const float* __restrict__ wexp,
                            const float* __restrict__ bexp, unsigned short* __restrict__ dynw,
                            float* __restrict__ dynb)
{
    __shared__ float ls[4*1152];
    __shared__ float lr[32*4];
    const int tid = threadIdx.x;
    const int co  = blockIdx.x & 127;
    const int bg  = blockIdx.x >> 7;

    if (tid < 32) {                   // recompute tiny router MLP per block (cheap)
        float s[6];
#pragma unroll
        for (int i = 0; i < 6; ++i) s[i] = stats[tid*6 + i];
        float h[16];
#pragma unroll
        for (int j = 0; j < 16; ++j) {
            float a = b1[j];
#pragma unroll
            for (int i = 0; i < 6; ++i) a += W1[j*6+i]*s[i];
            h[j] = a > 0.f ? a : 0.f;
        }
        float lg[4];
#pragma unroll
        for (int e = 0; e < 4; ++e) {
            float a = b2[e];
#pragma unroll
            for (int j = 0; j < 16; ++j) a += W2[e*16+j]*h[j];
            lg[e] = a;
        }
        float m = fmaxf(fmaxf(lg[0],lg[1]), fmaxf(lg[2],lg[3]));
        float ex[4], sum = 0.f;
#pragma unroll
        for (int e = 0; e < 4; ++e) { ex[e] = expf(lg[e]-m); sum += ex[e]; }
        float inv = 1.f / sum;
#pragma unroll
        for (int e = 0; e < 4; ++e) lr[tid*4+e] = ex[e]*inv;
    }
    for (int i = tid; i < 4*1152; i += 256) {
        int e = i / 1152, j = i - e*1152;
        ls[i] = wexp[((unsigned long long)(e*128 + co))*1152 + j];
    }
    __syncthreads();

    if (bg == 0 && tid < 32) {
        float sb = 0.f;
#pragma unroll
        for (int e = 0; e < 4; ++e) sb += lr[tid*4+e] * bexp[e*128 + co];
        dynb[tid*128 + co] = sb;
    }

    const int ci  = tid & 127;
    const int tp0 = tid >> 7;
    const int cic = ci >> 5;
    const int g   = (ci >> 3) & 3;
    const int jj  = ci & 7;
    const int mi  = co >> 4;
    const int l15 = co & 15;
    for (int bb = bg*8; bb < bg*8 + 8; ++bb) {
        float r0 = lr[bb*4+0], r1 = lr[bb*4+1], r2 = lr[bb*4+2], r3 = lr[bb*4+3];
#pragma unroll
        for (int pp = 0; pp < 5; ++pp) {
            int tap = 2*pp + tp0;
            if (tap < 9) {
                int j = ci*9 + tap;
                float v = r0*ls[j] + r1*ls[1152+j] + r2*ls[2*1152+j] + r3*ls[3*1152+j];
                dynw[((((unsigned long long)(bb*4 + cic)*9 + tap)*8 + mi)*64 + g*16 + l15)*8 + jj] = f2bf(v);
            }
        }
    }
}

// ---------------- kernel D: implicit-GEMM conv, bf16 MFMA ----------------
// grid 512 (32 b x 16 4-row tiles), 256 threads (4 waves), wave = 1 output
// row x full 128 co (mi=8, afrag[8]-preload r10 loop). Weights staged to LDS
// (6-deep rotation, one vmcnt(0)+s_barrier per 3-tap phase). Per-cic x
// restage: single-pass coalesced load -> pack -> aligned uint4 LDS write
// (raw layout; B-frag = 4x ds_read_b32, no transpose pass).
__global__ __launch_bounds__(256, 2) void conv_kernel(
    const float* __restrict__ x,
    const unsigned short* __restrict__ dynw,
    const float* __restrict__ dynb,
    float* __restrict__ out)
{
    // xs[row][pr(16)][68 words]: word stride per pr = 272 B, row = 4352 B
    __shared__ __align__(16) unsigned short xs[6*16*136];     // 26112 B
    __shared__ __align__(16) unsigned short wsm[6][4096];     // 24576 B

    const int tid  = threadIdx.x;
    const int wave = tid >> 6;       // output row within tile (0..3)
    const int lane = tid & 63;
    const int l15  = lane & 15;
    const int g    = lane >> 4;
    const int pr   = tid >> 4;       // pass1: ci-pair id (0..15)
    const int c4   = tid & 15;       // pass1: col quad (0..15)

    // bijective XCD swizzle (512 blocks, 8 XCDs -> 64 contiguous per XCD)
    int bidx = ((blockIdx.x & 7) << 6) | (blockIdx.x >> 3);
    const int b  = bidx >> 4;
    const int r0 = (bidx & 15) << 2;

    f32x4 acc[8][4];
#pragma unroll
    for (int mi = 0; mi < 8; ++mi)
#pragma unroll
        for (int ni = 0; ni < 4; ++ni) acc[mi][ni] = (f32x4){0.f,0.f,0.f,0.f};

    const float* xsrcb = x + (unsigned long long)b*(128ull*64*64);
    const unsigned short* wsrcb = dynw + (unsigned long long)b*(4ull*9*4096);

    // ---- restage pass: thread (pr,c4) loads ci {2pr, 2pr+1} x cols 4c4..4c4+3
    //      of row kk (coalesced 256B runs), packs bf16 pairs, writes one
    //      aligned uint4 into xs raw layout ----
#define P1ISSUE(kk)                                                            \
    do {                                                                       \
        int grow_ = r0 + (kk) - 1;                                             \
        int growc_ = grow_ < 0 ? 0 : (grow_ > 63 ? 63 : grow_);                \
        const float* xp_ = xsrcb + (unsigned)((cic_*32 + 2*pr)*4096)           \
                         + growc_*64 + c4*4;                                   \
        xv[(kk)&1][0] = *(const float4*)xp_;                                   \
        xv[(kk)&1][1] = *(const float4*)(xp_ + 4096);                          \
    } while (0)

#define P1PROC(kk)                                                             \
    do {                                                                       \
        int grow_ = r0 + (kk) - 1;                                             \
        bool oob_ = (grow_ < 0) || (grow_ > 63);                               \
        float4 va_ = xv[(kk)&1][0], vb_ = xv[(kk)&1][1];                       \
        unsigned w0_ = oob_ ? 0u : (f2bf(va_.x) | ((unsigned)f2bf(vb_.x) << 16)); \
        unsigned w1_ = oob_ ? 0u : (f2bf(va_.y) | ((unsigned)f2bf(vb_.y) << 16)); \
        unsigned w2_ = oob_ ? 0u : (f2bf(va_.z) | ((unsigned)f2bf(vb_.z) << 16)); \
        unsigned w3_ = oob_ ? 0u : (f2bf(va_.w) | ((unsigned)f2bf(vb_.w) << 16)); \
        *(uint4*)((char*)xs + (kk)*4352 + pr*272 + c4*16)                      \
            = make_uint4(w0_, w1_, w2_, w3_);                                  \
    } while (0)

    // ---- full restage: issue 3 W tiles first (L2-fast, drained early is
    //      harmless), rolling depth-2 load ladder, end barrier ----
#define XSTAGE(CIC_, WFIRST_)                                                  \
    do {                                                                       \
        const int cic_ = (CIC_);                                               \
        _Pragma("unroll")                                                      \
        for (int t = 0; t < 3; ++t) {                                          \
            const unsigned short* wsrc_ = wsrcb + (unsigned)(((WFIRST_) + t)*4096); \
            unsigned short* wd_ = wsm[((WFIRST_) + t) % 6];                    \
            gl2lds16(wsrc_ + (unsigned)tid*8,       wd_ + (unsigned)tid*8);    \
            gl2lds16(wsrc_ + (unsigned)(tid+256)*8, wd_ + (unsigned)(tid+256)*8); \
        }                                                                      \
        {                                                                      \
            float4 xv[2][2];                                                   \
            P1ISSUE(0); P1ISSUE(1);                                            \
            VMWAIT(2); P1PROC(0); P1ISSUE(2);                                  \
            VMWAIT(2); P1PROC(1); P1ISSUE(3);                                  \
            VMWAIT(2); P1PROC(2); P1ISSUE(4);                                  \
            VMWAIT(2); P1PROC(3); P1ISSUE(5);                                  \
            VMWAIT(2); P1PROC(4);                                              \
            VMWAIT(0); P1PROC(5);                                              \
        }                                                                      \
        LGKM0();                                                               \
        __builtin_amdgcn_s_barrier();                                          \
        __builtin_amdgcn_sched_barrier(0);                                     \
    } while (0)

    // prologue: zero halo words 64..67 of every (row, pr) -- covers right halo
    // (word 64) and left halo (word 65); never rewritten by restage.
    if (tid < 96)
        *(uint4*)((char*)xs + (tid >> 4)*4352 + (tid & 15)*272 + 256)
            = make_uint4(0,0,0,0);
    XSTAGE(0, 0);

#pragma unroll
    for (int p = 0; p < 12; ++p) {
        const int cic = p / 3;
        if (p > 0) {
            // bar A: everything issued >= 1 phase ago landed; cheap drain
            VMWAIT(0);
            __builtin_amdgcn_s_barrier();
            __builtin_amdgcn_sched_barrier(0);
        }
        if ((p % 3) == 0 && p > 0) {
            // cic boundary: restage xs (raw single pass) + W issue inside
            XSTAGE(cic, 3*p + 3);
        } else if (p < 11) {
            // steady: issue next phase's 3 weight tiles (reads {3p..3p+2}%6,
            // writes {3p+3..3p+5}%6 -- disjoint)
#pragma unroll
            for (int t = 0; t < 3; ++t) {
                const int s = 3*p + 3 + t;
                const unsigned short* wsrc = wsrcb + (unsigned)(s*4096);
                unsigned short* wd = wsm[s % 6];
                gl2lds16(wsrc + (unsigned)tid*8,       wd + (unsigned)tid*8);
                gl2lds16(wsrc + (unsigned)(tid+256)*8, wd + (unsigned)(tid+256)*8);
            }
        }
        // compute 3 taps (ky = p%3, kx = 0..2), no intervening sync
        const int ky   = p % 3;
        const int lrow = wave + ky;
        __builtin_amdgcn_s_setprio(1);
#pragma unroll
        for (int kx = 0; kx < 3; ++kx) {
            const unsigned short* wb = wsm[(3*p + kx) % 6];
            bf16x8 afrag[8];
#pragma unroll
            for (int mi = 0; mi < 8; ++mi)
                afrag[mi] = *(const bf16x8*)(wb + (unsigned)((mi*64 + lane)*8));
#pragma unroll
            for (int ni = 0; ni < 4; ++ni) {
                int c = 16*ni + l15 + kx - 1;           // -1..64
                int w = (c < 0) ? 65 : c;               // cndmask only ni=0,kx=0
                const char* bp = (const char*)xs + lrow*4352 + g*1088 + w*4;
                u32x4 bv;
                bv.x = *(const unsigned*)(bp);
                bv.y = *(const unsigned*)(bp + 272);
                bv.z = *(const unsigned*)(bp + 544);
                bv.w = *(const unsigned*)(bp + 816);
                bf16x8 bfrag = __builtin_bit_cast(bf16x8, bv);
#pragma unroll
                for (int mi = 0; mi < 8; ++mi)
                    acc[mi][ni] = __builtin_amdgcn_mfma_f32_16x16x32_bf16(
                                      afrag[mi], bfrag, acc[mi][ni], 0, 0, 0);
            }
        }
        __builtin_amdgcn_s_setprio(0);
    }

    // epilogue: co = 16*mi + g*4 + r ; y = r0 + wave ; x = 16*ni + l15
    const int y = r0 + wave;
#pragma unroll
    for (int mi = 0; mi < 8; ++mi) {
#pragma unroll
        for (int r = 0; r < 4; ++r) {
            int co = 16*mi + g*4 + r;
            float bias = dynb[b*128 + co];
            float* op = out + (((unsigned long long)(b*128 + co))*64 + y)*64;
#pragma unroll
            for (int ni = 0; ni < 4; ++ni)
                op[16*ni + l15] = acc[mi][ni][r] + bias;
        }
    }
#undef XSTAGE
#undef P1PROC
#undef P1ISSUE
}

extern "C" void kernel_launch(void* const* d_in, const int* in_sizes, int n_in,
                              void* d_out, int out_size, void* d_ws, size_t ws_size,
                              hipStream_t stream)
{
    const float* x     = (const float*)d_in[0];
    const float* stats = (const float*)d_in[1];
    const float* W1    = (const float*)d_in[2];
    const float* b1    = (const float*)d_in[3];
    const float* W2    = (const float*)d_in[4];
    const float* b2    = (const float*)d_in[5];
    const float* wexp  = (const float*)d_in[6];
    const float* bexp  = (const float*)d_in[7];
    float* out = (float*)d_out;

    char* ws = (char*)d_ws;
    float* dynb           = (float*)(ws + 512);                      // 16 KB
    unsigned short* dynw  = (unsigned short*)(ws + 32768);           // 9,437,184 B

    prep_kernel<<<512, 256, 0, stream>>>(stats, W1, b1, W2, b2, wexp, bexp, dynw, dynb);
    conv_kernel<<<512, 256, 0, stream>>>(x, dynw, dynb, out);
}

// Round 16
// 59.649 us; speedup vs baseline: 1.0982x; 1.0102x over previous
//
#include <hip/hip_runtime.h>
#include <hip/hip_bf16.h>

// StatDynamicConv2d: routing MLP -> expert-mixed 3x3 conv (per-sample weights)
// B=32, Cin=Cout=128, H=W=64, E=4, K=3, pad=1, stride=1.
//
// ws layout:
//   [512, 512+16384)       dynb[32][128] f32
//   [32768, +9437184)      dynw[32][4cic][9tap][8mi][64lane][8] bf16
//                          (MFMA A-fragment order)
// conv reads x (f32) directly. xs keeps the RAW staged layout
// [6 rows][16 ci-pair][68 words] (u32 = 2 bf16 ci for one col). B-frags are
// 4x ds_read_b32 at pr-stride 272B (conflict-free). T14 async restage:
// the 12 x loads for cic+1 are issued a full phase EARLY (ride under MFMA);
// the boundary phase only packs+writes (~500cy vs ~4800cy exposed ladder).

typedef short bf16x8 __attribute__((ext_vector_type(8)));
typedef float f32x4  __attribute__((ext_vector_type(4)));
typedef unsigned u32x4 __attribute__((ext_vector_type(4)));

#define VMWAIT(n) asm volatile("s_waitcnt vmcnt(" #n ")" ::: "memory")
#define LGKM0()   asm volatile("s_waitcnt lgkmcnt(0)" ::: "memory")

static __device__ __forceinline__ unsigned short f2bf(float f) {
    unsigned u = __float_as_uint(f);
    u = u + 0x7FFFu + ((u >> 16) & 1u);   // round-to-nearest-even
    return (unsigned short)(u >> 16);
}

static __device__ __forceinline__ void gl2lds16(const unsigned short* g, unsigned short* l) {
    __builtin_amdgcn_global_load_lds(
        (const __attribute__((address_space(1))) unsigned int*)g,
        (__attribute__((address_space(3))) unsigned int*)l,
        16, 0, 0);
}

// ---------------- kernel P: dynamic weights (router inlined) ----------------
// grid 512 (= 128 co x 4 bgroups), 256 threads
__global__ void prep_kernel(const float* __restrict__ stats, const float* __restrict__ W1,
                            const float* __restrict__ b1, const float* __restrict__ W2,
                            const float* __restrict__ b2, const float* __restrict__ wexp,
                            const float* __restrict__ bexp, unsigned short* __restrict__ dynw,
                            float* __restrict__ dynb)
{
    __shared__ float ls[4*1152];
    __shared__ float lr[32*4];
    const int tid = threadIdx.x;
    const int co  = blockIdx.x & 127;
    const int bg  = blockIdx.x >> 7;

    if (tid < 32) {                   // recompute tiny router MLP per block (cheap)
        float s[6];
#pragma unroll
        for (int i = 0; i < 6; ++i) s[i] = stats[tid*6 + i];
        float h[16];
#pragma unroll
        for (int j = 0; j < 16; ++j) {
            float a = b1[j];
#pragma unroll
            for (int i = 0; i < 6; ++i) a += W1[j*6+i]*s[i];
            h[j] = a > 0.f ? a : 0.f;
        }
        float lg[4];
#pragma unroll
        for (int e = 0; e < 4; ++e) {
            float a = b2[e];
#pragma unroll
            for (int j = 0; j < 16; ++j) a += W2[e*16+j]*h[j];
            lg[e] = a;
        }
        float m = fmaxf(fmaxf(lg[0],lg[1]), fmaxf(lg[2],lg[3]));
        float ex[4], sum = 0.f;
#pragma unroll
        for (int e = 0; e < 4; ++e) { ex[e] = expf(lg[e]-m); sum += ex[e]; }
        float inv = 1.f / sum;
#pragma unroll
        for (int e = 0; e < 4; ++e) lr[tid*4+e] = ex[e]*inv;
    }
    for (int i = tid; i < 4*1152; i += 256) {
        int e = i / 1152, j = i - e*1152;
        ls[i] = wexp[((unsigned long long)(e*128 + co))*1152 + j];
    }
    __syncthreads();

    if (bg == 0 && tid < 32) {
        float sb = 0.f;
#pragma unroll
        for (int e = 0; e < 4; ++e) sb += lr[tid*4+e] * bexp[e*128 + co];
        dynb[tid*128 + co] = sb;
    }

    const int ci  = tid & 127;
    const int tp0 = tid >> 7;
    const int cic = ci >> 5;
    const int g   = (ci >> 3) & 3;
    const int jj  = ci & 7;
    const int mi  = co >> 4;
    const int l15 = co & 15;
    for (int bb = bg*8; bb < bg*8 + 8; ++bb) {
        float r0 = lr[bb*4+0], r1 = lr[bb*4+1], r2 = lr[bb*4+2], r3 = lr[bb*4+3];
#pragma unroll
        for (int pp = 0; pp < 5; ++pp) {
            int tap = 2*pp + tp0;
            if (tap < 9) {
                int j = ci*9 + tap;
                float v = r0*ls[j] + r1*ls[1152+j] + r2*ls[2*1152+j] + r3*ls[3*1152+j];
                dynw[((((unsigned long long)(bb*4 + cic)*9 + tap)*8 + mi)*64 + g*16 + l15)*8 + jj] = f2bf(v);
            }
        }
    }
}

// ---------------- kernel D: implicit-GEMM conv, bf16 MFMA ----------------
// grid 512 (32 b x 16 4-row tiles), 256 threads (4 waves), wave = 1 output
// row x full 128 co. Weights staged to LDS (6-deep rotation, one
// vmcnt(0)+s_barrier per 3-tap phase). x restage: loads issued one full
// phase early (T14), boundary phase = pack + aligned uint4 LDS write only.
__global__ __launch_bounds__(256, 2) void conv_kernel(
    const float* __restrict__ x,
    const unsigned short* __restrict__ dynw,
    const float* __restrict__ dynb,
    float* __restrict__ out)
{
    // xs[row][pr(16)][68 words]: word stride per pr = 272 B, row = 4352 B
    __shared__ __align__(16) unsigned short xs[6*16*136];     // 26112 B
    __shared__ __align__(16) unsigned short wsm[6][4096];     // 24576 B

    const int tid  = threadIdx.x;
    const int wave = tid >> 6;       // output row within tile (0..3)
    const int lane = tid & 63;
    const int l15  = lane & 15;
    const int g    = lane >> 4;
    const int pr   = tid >> 4;       // staging: ci-pair id (0..15)
    const int c4   = tid & 15;       // staging: col quad (0..15)

    // bijective XCD swizzle (512 blocks, 8 XCDs -> 64 contiguous per XCD)
    int bidx = ((blockIdx.x & 7) << 6) | (blockIdx.x >> 3);
    const int b  = bidx >> 4;
    const int r0 = (bidx & 15) << 2;

    f32x4 acc[8][4];
#pragma unroll
    for (int mi = 0; mi < 8; ++mi)
#pragma unroll
        for (int ni = 0; ni < 4; ++ni) acc[mi][ni] = (f32x4){0.f,0.f,0.f,0.f};

    const float* xsrcb = x + (unsigned long long)b*(128ull*64*64);
    const unsigned short* wsrcb = dynw + (unsigned long long)b*(4ull*9*4096);

    float4 xv[6][2];   // early-issued staging window (static indices only)

#define P1ISSUE(CIC_, KK)                                                      \
    do {                                                                       \
        int grow_ = r0 + (KK) - 1;                                             \
        int growc_ = grow_ < 0 ? 0 : (grow_ > 63 ? 63 : grow_);                \
        const float* xp_ = xsrcb + (unsigned)(((CIC_)*32 + 2*pr)*4096)         \
                         + growc_*64 + c4*4;                                   \
        xv[KK][0] = *(const float4*)xp_;                                       \
        xv[KK][1] = *(const float4*)(xp_ + 4096);                              \
    } while (0)

#define P1PROC(KK)                                                             \
    do {                                                                       \
        int grow_ = r0 + (KK) - 1;                                             \
        bool oob_ = (grow_ < 0) || (grow_ > 63);                               \
        float4 va_ = xv[KK][0], vb_ = xv[KK][1];                               \
        unsigned w0_ = oob_ ? 0u : (f2bf(va_.x) | ((unsigned)f2bf(vb_.x) << 16)); \
        unsigned w1_ = oob_ ? 0u : (f2bf(va_.y) | ((unsigned)f2bf(vb_.y) << 16)); \
        unsigned w2_ = oob_ ? 0u : (f2bf(va_.z) | ((unsigned)f2bf(vb_.z) << 16)); \
        unsigned w3_ = oob_ ? 0u : (f2bf(va_.w) | ((unsigned)f2bf(vb_.w) << 16)); \
        *(uint4*)((char*)xs + (KK)*4352 + pr*272 + c4*16)                      \
            = make_uint4(w0_, w1_, w2_, w3_);                                  \
    } while (0)

    // prologue: zero halo words 64..67 of every (row, pr); stage cic0 + W(0..2)
    if (tid < 96)
        *(uint4*)((char*)xs + (tid >> 4)*4352 + (tid & 15)*272 + 256)
            = make_uint4(0,0,0,0);
    P1ISSUE(0,0); P1ISSUE(0,1); P1ISSUE(0,2);
    P1ISSUE(0,3); P1ISSUE(0,4); P1ISSUE(0,5);
#pragma unroll
    for (int t = 0; t < 3; ++t) {
        const unsigned short* wsrc = wsrcb + (unsigned)(t*4096);
        gl2lds16(wsrc + (unsigned)tid*8,       wsm[t] + (unsigned)tid*8);
        gl2lds16(wsrc + (unsigned)(tid+256)*8, wsm[t] + (unsigned)(tid+256)*8);
    }
    VMWAIT(6);   // all 12 x loads landed (6 W remain in flight)
    P1PROC(0); P1PROC(1); P1PROC(2); P1PROC(3); P1PROC(4); P1PROC(5);
    VMWAIT(0);   // W(0..2) in LDS
    LGKM0();
    __builtin_amdgcn_s_barrier();
    __builtin_amdgcn_sched_barrier(0);

#pragma unroll
    for (int p = 0; p < 12; ++p) {
        if (p > 0) {
            // bar A: everything issued >= 1 phase ago (W and early x) landed
            VMWAIT(0);
            __builtin_amdgcn_s_barrier();
            __builtin_amdgcn_sched_barrier(0);
        }
        if ((p % 3) == 0 && p > 0) {
            // boundary: pack the early-loaded x into xs (old readers done at
            // bar A), then one barrier before compute. No load waits here.
            P1PROC(0); P1PROC(1); P1PROC(2); P1PROC(3); P1PROC(4); P1PROC(5);
            LGKM0();
            __builtin_amdgcn_s_barrier();
            __builtin_amdgcn_sched_barrier(0);
        }
        if (p < 11) {
            // issue next phase's 3 weight tiles (reads {3p..3p+2}%6,
            // writes {3p+3..3p+5}%6 -- disjoint)
#pragma unroll
            for (int t = 0; t < 3; ++t) {
                const int s = 3*p + 3 + t;
                const unsigned short* wsrc = wsrcb + (unsigned)(s*4096);
                unsigned short* wd = wsm[s % 6];
                gl2lds16(wsrc + (unsigned)tid*8,       wd + (unsigned)tid*8);
                gl2lds16(wsrc + (unsigned)(tid+256)*8, wd + (unsigned)(tid+256)*8);
            }
        }
        if ((p % 3) == 2 && p < 9) {
            // T14: issue next cic's 12 x loads NOW; they ride under this
            // phase's MFMAs and land before the boundary's bar A.
            const int nc = p/3 + 1;
            P1ISSUE(nc,0); P1ISSUE(nc,1); P1ISSUE(nc,2);
            P1ISSUE(nc,3); P1ISSUE(nc,4); P1ISSUE(nc,5);
            __builtin_amdgcn_sched_barrier(0);   // pin issue before MFMA region
        }
        // compute 3 taps (ky = p%3, kx = 0..2), no intervening sync
        const int ky   = p % 3;
        const int lrow = wave + ky;
        __builtin_amdgcn_s_setprio(1);
#pragma unroll
        for (int kx = 0; kx < 3; ++kx) {
            const unsigned short* wb = wsm[(3*p + kx) % 6];
            u32x4 bv[4];
#pragma unroll
            for (int ni = 0; ni < 4; ++ni) {
                int c = 16*ni + l15 + kx - 1;           // -1..64
                int w = (c < 0) ? 65 : c;               // cndmask only ni=0,kx=0
                const char* bp = (const char*)xs + lrow*4352 + g*1088 + w*4;
                bv[ni].x = *(const unsigned*)(bp);
                bv[ni].y = *(const unsigned*)(bp + 272);
                bv[ni].z = *(const unsigned*)(bp + 544);
                bv[ni].w = *(const unsigned*)(bp + 816);
            }
#pragma unroll
            for (int mi = 0; mi < 8; ++mi) {
                bf16x8 afrag = *(const bf16x8*)(wb + (unsigned)((mi*64 + lane)*8));
#pragma unroll
                for (int ni = 0; ni < 4; ++ni)
                    acc[mi][ni] = __builtin_amdgcn_mfma_f32_16x16x32_bf16(
                                      afrag, __builtin_bit_cast(bf16x8, bv[ni]),
                                      acc[mi][ni], 0, 0, 0);
            }
        }
        __builtin_amdgcn_s_setprio(0);
    }

    // epilogue: co = 16*mi + g*4 + r ; y = r0 + wave ; x = 16*ni + l15
    const int y = r0 + wave;
#pragma unroll
    for (int mi = 0; mi < 8; ++mi) {
#pragma unroll
        for (int r = 0; r < 4; ++r) {
            int co = 16*mi + g*4 + r;
            float bias = dynb[b*128 + co];
            float* op = out + (((unsigned long long)(b*128 + co))*64 + y)*64;
#pragma unroll
            for (int ni = 0; ni < 4; ++ni)
                op[16*ni + l15] = acc[mi][ni][r] + bias;
        }
    }
#undef P1PROC
#undef P1ISSUE
}

extern "C" void kernel_launch(void* const* d_in, const int* in_sizes, int n_in,
                              void* d_out, int out_size, void* d_ws, size_t ws_size,
                              hipStream_t stream)
{
    const float* x     = (const float*)d_in[0];
    const float* stats = (const float*)d_in[1];
    const float* W1    = (const float*)d_in[2];
    const float* b1    = (const float*)d_in[3];
    const float* W2    = (const float*)d_in[4];
    const float* b2    = (const float*)d_in[5];
    const float* wexp  = (const float*)d_in[6];
    const float* bexp  = (const float*)d_in[7];
    float* out = (float*)d_out;

    char* ws = (char*)d_ws;
    float* dynb           = (float*)(ws + 512);                      // 16 KB
    unsigned short* dynw  = (unsigned short*)(ws + 32768);           // 9,437,184 B

    prep_kernel<<<512, 256, 0, stream>>>(stats, W1, b1, W2, b2, wexp, bexp, dynw, dynb);
    conv_kernel<<<512, 256, 0, stream>>>(x, dynw, dynb, out);
}

// Round 17
// 58.903 us; speedup vs baseline: 1.1121x; 1.0127x over previous
//
#include <hip/hip_runtime.h>
#include <hip/hip_bf16.h>

// StatDynamicConv2d: routing MLP -> expert-mixed 3x3 conv (per-sample weights)
// B=32, Cin=Cout=128, H=W=64, E=4, K=3, pad=1, stride=1.
//
// ws layout:
//   [512, 512+16384)       dynb[32][128] f32
//   [32768, +9437184)      dynw[32][4cic][9tap][8mi][64lane][8] bf16
//                          (MFMA A-fragment order)
// conv reads x (f32) directly. xs layout [6 rows][66 cols][80 B]: each col's
// 16 ci-pair u32 words are CONTIGUOUS -> bfrag = single ds_read_b128
// (conflict-free); staging writes 4x ds_write_b32. Staging registers split
// by row liveness: rows 0-1 (16 regs, q=1->q=2 in-place pack) and rows 2-5
// (32 regs, q=2->boundary pack) so no window exceeds 32 regs (no spill).

typedef short bf16x8 __attribute__((ext_vector_type(8)));
typedef float f32x4  __attribute__((ext_vector_type(4)));

#define VMWAIT(n) asm volatile("s_waitcnt vmcnt(" #n ")" ::: "memory")
#define LGKM0()   asm volatile("s_waitcnt lgkmcnt(0)" ::: "memory")

static __device__ __forceinline__ unsigned short f2bf(float f) {
    unsigned u = __float_as_uint(f);
    u = u + 0x7FFFu + ((u >> 16) & 1u);   // round-to-nearest-even
    return (unsigned short)(u >> 16);
}

static __device__ __forceinline__ void gl2lds16(const unsigned short* g, unsigned short* l) {
    __builtin_amdgcn_global_load_lds(
        (const __attribute__((address_space(1))) unsigned int*)g,
        (__attribute__((address_space(3))) unsigned int*)l,
        16, 0, 0);
}

// ---------------- kernel P: dynamic weights (router inlined) ----------------
// grid 512 (= 128 co x 4 bgroups), 256 threads
__global__ void prep_kernel(const float* __restrict__ stats, const float* __restrict__ W1,
                            const float* __restrict__ b1, const float* __restrict__ W2,
                            const float* __restrict__ b2, const float* __restrict__ wexp,
                            const float* __restrict__ bexp, unsigned short* __restrict__ dynw,
                            float* __restrict__ dynb)
{
    __shared__ float ls[4*1152];
    __shared__ float lr[32*4];
    const int tid = threadIdx.x;
    const int co  = blockIdx.x & 127;
    const int bg  = blockIdx.x >> 7;

    if (tid < 32) {                   // recompute tiny router MLP per block (cheap)
        float s[6];
#pragma unroll
        for (int i = 0; i < 6; ++i) s[i] = stats[tid*6 + i];
        float h[16];
#pragma unroll
        for (int j = 0; j < 16; ++j) {
            float a = b1[j];
#pragma unroll
            for (int i = 0; i < 6; ++i) a += W1[j*6+i]*s[i];
            h[j] = a > 0.f ? a : 0.f;
        }
        float lg[4];
#pragma unroll
        for (int e = 0; e < 4; ++e) {
            float a = b2[e];
#pragma unroll
            for (int j = 0; j < 16; ++j) a += W2[e*16+j]*h[j];
            lg[e] = a;
        }
        float m = fmaxf(fmaxf(lg[0],lg[1]), fmaxf(lg[2],lg[3]));
        float ex[4], sum = 0.f;
#pragma unroll
        for (int e = 0; e < 4; ++e) { ex[e] = expf(lg[e]-m); sum += ex[e]; }
        float inv = 1.f / sum;
#pragma unroll
        for (int e = 0; e < 4; ++e) lr[tid*4+e] = ex[e]*inv;
    }
    for (int i = tid; i < 4*1152; i += 256) {
        int e = i / 1152, j = i - e*1152;
        ls[i] = wexp[((unsigned long long)(e*128 + co))*1152 + j];
    }
    __syncthreads();

    if (bg == 0 && tid < 32) {
        float sb = 0.f;
#pragma unroll
        for (int e = 0; e < 4; ++e) sb += lr[tid*4+e] * bexp[e*128 + co];
        dynb[tid*128 + co] = sb;
    }

    const int ci  = tid & 127;
    const int tp0 = tid >> 7;
    const int cic = ci >> 5;
    const int g   = (ci >> 3) & 3;
    const int jj  = ci & 7;
    const int mi  = co >> 4;
    const int l15 = co & 15;
    for (int bb = bg*8; bb < bg*8 + 8; ++bb) {
        float r0 = lr[bb*4+0], r1 = lr[bb*4+1], r2 = lr[bb*4+2], r3 = lr[bb*4+3];
#pragma unroll
        for (int pp = 0; pp < 5; ++pp) {
            int tap = 2*pp + tp0;
            if (tap < 9) {
                int j = ci*9 + tap;
                float v = r0*ls[j] + r1*ls[1152+j] + r2*ls[2*1152+j] + r3*ls[3*1152+j];
                dynw[((((unsigned long long)(bb*4 + cic)*9 + tap)*8 + mi)*64 + g*16 + l15)*8 + jj] = f2bf(v);
            }
        }
    }
}

// ---------------- kernel D: implicit-GEMM conv, bf16 MFMA ----------------
// grid 512 (32 b x 16 4-row tiles), 256 threads (4 waves), wave = 1 output
// row x full 128 co. Weights staged to LDS (6-deep rotation, one
// vmcnt(0)+s_barrier per 3-tap phase). x staged direct from f32 global with
// liveness-split early-issued windows; xs packed col-contiguous.
__global__ __launch_bounds__(256, 2) void conv_kernel(
    const float* __restrict__ x,
    const unsigned short* __restrict__ dynw,
    const float* __restrict__ dynb,
    float* __restrict__ out)
{
    // xs[row][col(66)][40 u16 = 80B]: row stride 5280 B, col stride 80 B.
    // words 0..15 of each col = ci-pairs (u32, lo=ci even, hi=ci odd).
    __shared__ __align__(16) unsigned short xs[6*66*40];      // 31680 B
    __shared__ __align__(16) unsigned short wsm[6][4096];     // 49152 B

    const int tid  = threadIdx.x;
    const int wave = tid >> 6;       // output row within tile (0..3)
    const int lane = tid & 63;
    const int l15  = lane & 15;
    const int g    = lane >> 4;
    const int pr   = tid >> 4;       // staging: ci-pair id (0..15)
    const int c4   = tid & 15;       // staging: col quad (0..15)

    // bijective XCD swizzle (512 blocks, 8 XCDs -> 64 contiguous per XCD)
    int bidx = ((blockIdx.x & 7) << 6) | (blockIdx.x >> 3);
    const int b  = bidx >> 4;
    const int r0 = (bidx & 15) << 2;

    f32x4 acc[8][4];
#pragma unroll
    for (int mi = 0; mi < 8; ++mi)
#pragma unroll
        for (int ni = 0; ni < 4; ++ni) acc[mi][ni] = (f32x4){0.f,0.f,0.f,0.f};

    const float* xsrcb = x + (unsigned long long)b*(128ull*64*64);
    const unsigned short* wsrcb = dynw + (unsigned long long)b*(4ull*9*4096);

    float4 xvA[2][2];   // rows 0-1 window (16 regs)
    float4 xvB[4][2];   // rows 2-5 window (32 regs)

#define XISSUE(CIC_, KK, DST)                                                  \
    do {                                                                       \
        int grow_ = r0 + (KK) - 1;                                             \
        int growc_ = grow_ < 0 ? 0 : (grow_ > 63 ? 63 : grow_);                \
        const float* xp_ = xsrcb + (unsigned)(((CIC_)*32 + 2*pr)*4096)         \
                         + growc_*64 + c4*4;                                   \
        DST[0] = *(const float4*)xp_;                                          \
        DST[1] = *(const float4*)(xp_ + 4096);                                 \
    } while (0)

#define XPACK(KK, SRC)                                                         \
    do {                                                                       \
        int grow_ = r0 + (KK) - 1;                                             \
        bool oob_ = (grow_ < 0) || (grow_ > 63);                               \
        float4 va_ = SRC[0], vb_ = SRC[1];                                     \
        unsigned w0_ = oob_ ? 0u : (f2bf(va_.x) | ((unsigned)f2bf(vb_.x) << 16)); \
        unsigned w1_ = oob_ ? 0u : (f2bf(va_.y) | ((unsigned)f2bf(vb_.y) << 16)); \
        unsigned w2_ = oob_ ? 0u : (f2bf(va_.z) | ((unsigned)f2bf(vb_.z) << 16)); \
        unsigned w3_ = oob_ ? 0u : (f2bf(va_.w) | ((unsigned)f2bf(vb_.w) << 16)); \
        char* bp_ = (char*)xs + (KK)*5280 + (4*c4 + 1)*80 + pr*4;              \
        *(unsigned*)(bp_)       = w0_;                                         \
        *(unsigned*)(bp_ + 80)  = w1_;                                         \
        *(unsigned*)(bp_ + 160) = w2_;                                         \
        *(unsigned*)(bp_ + 240) = w3_;                                         \
    } while (0)

    // prologue: zero halo cols 0 and 65 (80 B x 6 rows x 2 cols = 60 uint4)
    if (tid < 60) {
        int r = tid / 10, rem = tid - r*10;
        int col = (rem < 5) ? 0 : 65;
        int qq  = (rem < 5) ? rem : rem - 5;
        *(uint4*)((char*)xs + r*5280 + col*80 + qq*16) = make_uint4(0,0,0,0);
    }
    // issue all 6 rows of cic 0, then W(0..2); pack after counted wait
    XISSUE(0,0,xvA[0]); XISSUE(0,1,xvA[1]);
    XISSUE(0,2,xvB[0]); XISSUE(0,3,xvB[1]); XISSUE(0,4,xvB[2]); XISSUE(0,5,xvB[3]);
#pragma unroll
    for (int t = 0; t < 3; ++t) {
        const unsigned short* wsrc = wsrcb + (unsigned)(t*4096);
        gl2lds16(wsrc + (unsigned)tid*8,       wsm[t] + (unsigned)tid*8);
        gl2lds16(wsrc + (unsigned)(tid+256)*8, wsm[t] + (unsigned)(tid+256)*8);
    }
    VMWAIT(6);   // all 12 x loads landed (6 W gl2lds remain in flight)
    XPACK(0,xvA[0]); XPACK(1,xvA[1]);
    XPACK(2,xvB[0]); XPACK(3,xvB[1]); XPACK(4,xvB[2]); XPACK(5,xvB[3]);
    VMWAIT(0);   // W(0..2) in LDS
    LGKM0();
    __builtin_amdgcn_s_barrier();
    __builtin_amdgcn_sched_barrier(0);

#pragma unroll
    for (int p = 0; p < 12; ++p) {
        const int cic = p / 3;
        const int q   = p % 3;
        if (p > 0) {
            // bar A: everything in flight was issued >= 1 phase ago
            VMWAIT(0);
            __builtin_amdgcn_s_barrier();
            __builtin_amdgcn_sched_barrier(0);
        }
        if (q == 0 && p > 0) {
            // boundary: pack rows 2-5 (loads landed at bar A); old readers of
            // rows 2-5 finished before bar A. Then make visible.
            XPACK(2,xvB[0]); XPACK(3,xvB[1]); XPACK(4,xvB[2]); XPACK(5,xvB[3]);
            LGKM0();
            __builtin_amdgcn_s_barrier();
            __builtin_amdgcn_sched_barrier(0);
        }
        if (p < 11) {
            // issue next phase's 3 weight tiles (reads {3p..3p+2}%6,
            // writes {3p+3..3p+5}%6 -- disjoint)
#pragma unroll
            for (int t = 0; t < 3; ++t) {
                const int s = 3*p + 3 + t;
                const unsigned short* wsrc = wsrcb + (unsigned)(s*4096);
                unsigned short* wd = wsm[s % 6];
                gl2lds16(wsrc + (unsigned)tid*8,       wd + (unsigned)tid*8);
                gl2lds16(wsrc + (unsigned)(tid+256)*8, wd + (unsigned)(tid+256)*8);
            }
        }
        if (q == 1 && cic < 3) {
            // early-issue rows 0-1 of next cic (16 regs, ride under MFMA)
            XISSUE(cic+1,0,xvA[0]); XISSUE(cic+1,1,xvA[1]);
            __builtin_amdgcn_sched_barrier(0);
        }
        if (q == 2 && cic < 3) {
            // rows 0-1 old are dead after q=1 -> pack new rows 0-1 in place
            // (loads landed at this phase's bar A); visibility via boundary
            // LGKM0+barrier. Then early-issue rows 2-5 (32 regs).
            XPACK(0,xvA[0]); XPACK(1,xvA[1]);
            XISSUE(cic+1,2,xvB[0]); XISSUE(cic+1,3,xvB[1]);
            XISSUE(cic+1,4,xvB[2]); XISSUE(cic+1,5,xvB[3]);
            __builtin_amdgcn_sched_barrier(0);
        }
        // compute 3 taps (ky = q, kx = 0..2), no intervening sync
        const int lrow = wave + q;
        __builtin_amdgcn_s_setprio(1);
#pragma unroll
        for (int kx = 0; kx < 3; ++kx) {
            const unsigned short* wb = wsm[(3*p + kx) % 6];
            bf16x8 bfr[4];
#pragma unroll
            for (int ni = 0; ni < 4; ++ni) {
                int lcol = 16*ni + l15 + kx;   // 0..65 (halo cols are zeros)
                bfr[ni] = *(const bf16x8*)((const char*)xs
                              + lrow*5280 + lcol*80 + g*16);
            }
#pragma unroll
            for (int mi = 0; mi < 8; ++mi) {
                bf16x8 afrag = *(const bf16x8*)(wb + (unsigned)((mi*64 + lane)*8));
#pragma unroll
                for (int ni = 0; ni < 4; ++ni)
                    acc[mi][ni] = __builtin_amdgcn_mfma_f32_16x16x32_bf16(
                                      afrag, bfr[ni], acc[mi][ni], 0, 0, 0);
            }
        }
        __builtin_amdgcn_s_setprio(0);
    }

    // epilogue: co = 16*mi + g*4 + r ; y = r0 + wave ; x = 16*ni + l15
    const int y = r0 + wave;
#pragma unroll
    for (int mi = 0; mi < 8; ++mi) {
#pragma unroll
        for (int r = 0; r < 4; ++r) {
            int co = 16*mi + g*4 + r;
            float bias = dynb[b*128 + co];
            float* op = out + (((unsigned long long)(b*128 + co))*64 + y)*64;
#pragma unroll
            for (int ni = 0; ni < 4; ++ni)
                op[16*ni + l15] = acc[mi][ni][r] + bias;
        }
    }
#undef XPACK
#undef XISSUE
}

extern "C" void kernel_launch(void* const* d_in, const int* in_sizes, int n_in,
                              void* d_out, int out_size, void* d_ws, size_t ws_size,
                              hipStream_t stream)
{
    const float* x     = (const float*)d_in[0];
    const float* stats = (const float*)d_in[1];
    const float* W1    = (const float*)d_in[2];
    const float* b1    = (const float*)d_in[3];
    const float* W2    = (const float*)d_in[4];
    const float* b2    = (const float*)d_in[5];
    const float* wexp  = (const float*)d_in[6];
    const float* bexp  = (const float*)d_in[7];
    float* out = (float*)d_out;

    char* ws = (char*)d_ws;
    float* dynb           = (float*)(ws + 512);                      // 16 KB
    unsigned short* dynw  = (unsigned short*)(ws + 32768);           // 9,437,184 B

    prep_kernel<<<512, 256, 0, stream>>>(stats, W1, b1, W2, b2, wexp, bexp, dynw, dynb);
    conv_kernel<<<512, 256, 0, stream>>>(x, dynw, dynb, out);
}